// Round 1
// baseline (638.031 us; speedup 1.0000x reference)
//
#include <hip/hip_runtime.h>

// ---------------- kernels ----------------

__global__ void k_deg(const int* __restrict__ dstv, int* __restrict__ deg, int e) {
  int i = blockIdx.x * blockDim.x + threadIdx.x;
  if (i < e) atomicAdd(&deg[dstv[i]], 1);
}

__global__ void k_scan1(const int* __restrict__ deg, int* __restrict__ rp,
                        int* __restrict__ bsum, int n) {
  __shared__ int s[1024];
  int i = blockIdx.x * 1024 + threadIdx.x;
  int v = (i < n) ? deg[i] : 0;
  s[threadIdx.x] = v;
  __syncthreads();
  for (int off = 1; off < 1024; off <<= 1) {
    int t = (threadIdx.x >= off) ? s[threadIdx.x - off] : 0;
    __syncthreads();
    s[threadIdx.x] += t;
    __syncthreads();
  }
  if (i < n) rp[i] = s[threadIdx.x] - v;  // exclusive within block
  if (threadIdx.x == 1023) bsum[blockIdx.x] = s[1023];
}

__global__ void k_scan2(int* __restrict__ bsum, int nb) {
  __shared__ int s[128];
  int v = (threadIdx.x < nb) ? bsum[threadIdx.x] : 0;
  s[threadIdx.x] = v;
  __syncthreads();
  for (int off = 1; off < 128; off <<= 1) {
    int t = (threadIdx.x >= off) ? s[threadIdx.x - off] : 0;
    __syncthreads();
    s[threadIdx.x] += t;
    __syncthreads();
  }
  if (threadIdx.x < nb) bsum[threadIdx.x] = s[threadIdx.x] - v;  // exclusive
}

__global__ void k_scan3(int* __restrict__ rp, const int* __restrict__ bsum, int n, int e) {
  int i = blockIdx.x * 1024 + threadIdx.x;
  if (i < n) rp[i] += bsum[blockIdx.x];
  if (i == 0) rp[n] = e;
}

__global__ void k_dinv(const int* __restrict__ deg, float* __restrict__ dinv, int n) {
  int i = blockIdx.x * blockDim.x + threadIdx.x;
  if (i < n) dinv[i] = rsqrtf((float)(deg[i] + 1));  // +1 self loop, always > 0
}

__global__ void k_scatter(const int* __restrict__ src, const int* __restrict__ dstv,
                          const float* __restrict__ x, const float* __restrict__ dinv,
                          float* __restrict__ zsum, const int* __restrict__ rp,
                          int* __restrict__ cursor, int* __restrict__ col, int e) {
  int i = blockIdx.x * blockDim.x + threadIdx.x;
  if (i < e) {
    int s = src[i], d = dstv[i];
    atomicAdd(&zsum[d], x[s] * dinv[s]);
    int pos = atomicAdd(&cursor[d], 1);
    col[rp[d] + pos] = s;
  }
}

__global__ void k_z(const float* __restrict__ x, const float* __restrict__ dinv,
                    const float* __restrict__ zsum, float2* __restrict__ zd, int n) {
  int i = blockIdx.x * blockDim.x + threadIdx.x;
  if (i < n) {
    float di = dinv[i];
    float z = di * (zsum[i] + x[i] * di);
    zd[i] = make_float2(z, di);
  }
}

// one wave per node: lanes = features (2 each), neighbors loaded lane-parallel
// then broadcast via shfl. g[v,f] = dinv[v] * ( sum_u relu(z_u*W1[f]+b1[f])*dinv_u
//                                               + relu(z_v*W1[f]+b1[f])*dinv_v )
__global__ void k_agg(const float2* __restrict__ zd, const int* __restrict__ rp,
                      const int* __restrict__ col, const float* __restrict__ W1,
                      const float* __restrict__ b1, float* __restrict__ g, int n) {
  int wid = (int)((blockIdx.x * (size_t)blockDim.x + threadIdx.x) >> 6);
  int lane = threadIdx.x & 63;
  if (wid >= n) return;
  float w0 = W1[lane], w1 = W1[lane + 64];
  float c0 = b1[lane], c1 = b1[lane + 64];
  float a0 = 0.f, a1 = 0.f;
  int jb = rp[wid], je = rp[wid + 1];
  for (int j0 = jb; j0 < je; j0 += 64) {
    int cnt = min(64, je - j0);
    float px = 0.f, py = 0.f;
    if (j0 + lane < je) {
      int u = col[j0 + lane];
      float2 p = zd[u];
      px = p.x; py = p.y;
    }
    for (int i = 0; i < cnt; ++i) {
      float zx = __shfl(px, i);
      float dy = __shfl(py, i);
      float h0 = fmaxf(zx * w0 + c0, 0.f);
      float h1 = fmaxf(zx * w1 + c1, 0.f);
      a0 += h0 * dy;
      a1 += h1 * dy;
    }
  }
  float2 pv = zd[wid];
  a0 += fmaxf(pv.x * w0 + c0, 0.f) * pv.y;
  a1 += fmaxf(pv.x * w1 + c1, 0.f) * pv.y;
  g[(size_t)wid * 128 + lane] = a0 * pv.y;
  g[(size_t)wid * 128 + lane + 64] = a1 * pv.y;
}

// out[v,o] = relu( sum_k g[v,k]*W2[k,o] + b2[o] )
// block: 64 nodes x 64 outputs, 256 threads, acc[4][4]/thread.
// gl: [k][m] transposed, XOR-swizzled on m-group; wl: [k][o] linear.
__global__ void k_gemm(const float* __restrict__ g, const float* __restrict__ W2,
                       const float* __restrict__ b2, float* __restrict__ out, int n) {
  extern __shared__ float smem[];
  float* gl = smem;          // 128*64
  float* wl = smem + 8192;   // 128*64
  int tid = threadIdx.x;
  int m_base = blockIdx.x * 64;
  int o_base = blockIdx.y * 64;

  // stage W2 tile [128 k][64 o]
  {
    int k = tid >> 1;
    int half = tid & 1;
    const float* wsrc = W2 + (size_t)k * 256 + o_base + half * 32;
    float* wdst = wl + k * 64 + half * 32;
#pragma unroll
    for (int i = 0; i < 8; i++)
      *(float4*)(wdst + i * 4) = *(const float4*)(wsrc + i * 4);
  }
  // stage g tile transposed: gl[k][m], swizzled
  {
    int row = tid >> 2;                 // node within tile, 0..63
    int cseg = (tid & 3) * 32;          // 32 k's per thread
    int v = m_base + row;
#pragma unroll
    for (int i = 0; i < 8; i++) {
      int c = cseg + i * 4;
      float4 val = make_float4(0.f, 0.f, 0.f, 0.f);
      if (v < n) val = *(const float4*)(g + (size_t)v * 128 + c);
      float vv[4] = {val.x, val.y, val.z, val.w};
#pragma unroll
      for (int j = 0; j < 4; j++) {
        int k = c + j;
        int sw = ((((row >> 2) ^ (k & 15)) << 2) | (row & 3));
        gl[k * 64 + sw] = vv[j];
      }
    }
  }
  __syncthreads();

  int mg = tid & 15;           // m-group: nodes mg*4..mg*4+3
  int o0 = (tid >> 4) * 4;     // 4 outputs
  float acc[4][4];
#pragma unroll
  for (int i = 0; i < 4; i++)
#pragma unroll
    for (int j = 0; j < 4; j++) acc[i][j] = 0.f;

#pragma unroll 4
  for (int k = 0; k < 128; k++) {
    float4 a = *(const float4*)(gl + k * 64 + ((mg ^ (k & 15)) << 2));
    float4 w = *(const float4*)(wl + k * 64 + o0);
    float av[4] = {a.x, a.y, a.z, a.w};
    float wv[4] = {w.x, w.y, w.z, w.w};
#pragma unroll
    for (int i = 0; i < 4; i++)
#pragma unroll
      for (int j = 0; j < 4; j++) acc[i][j] += av[i] * wv[j];
  }

  float4 bb = *(const float4*)(b2 + o_base + o0);
  float bv[4] = {bb.x, bb.y, bb.z, bb.w};
#pragma unroll
  for (int i = 0; i < 4; i++) {
    int v = m_base + mg * 4 + i;
    if (v < n) {
      float4 r;
      r.x = fmaxf(acc[i][0] + bv[0], 0.f);
      r.y = fmaxf(acc[i][1] + bv[1], 0.f);
      r.z = fmaxf(acc[i][2] + bv[2], 0.f);
      r.w = fmaxf(acc[i][3] + bv[3], 0.f);
      *(float4*)(out + (size_t)v * 256 + o_base + o0) = r;
    }
  }
}

// ---------------- launch ----------------

extern "C" void kernel_launch(void* const* d_in, const int* in_sizes, int n_in,
                              void* d_out, int out_size, void* d_ws, size_t ws_size,
                              hipStream_t stream) {
  const float* x  = (const float*)d_in[0];
  const int*   ei = (const int*)d_in[1];
  const float* W1 = (const float*)d_in[2];
  const float* b1 = (const float*)d_in[3];
  const float* W2 = (const float*)d_in[4];
  const float* b2 = (const float*)d_in[5];
  float* out = (float*)d_out;

  int n = in_sizes[0];       // 100000 nodes
  int e = in_sizes[1] / 2;   // 3200000 edges
  const int* src = ei;
  const int* dst = ei + e;

  // workspace layout (256B-aligned chunks)
  char* ws = (char*)d_ws;
  size_t off = 0;
  auto take = [&](size_t bytes) -> char* {
    char* p = ws + off;
    off = (off + bytes + 255) & ~(size_t)255;
    return p;
  };
  int*    deg    = (int*)take((size_t)n * 4);
  int*    cursor = (int*)take((size_t)n * 4);
  float*  zsum   = (float*)take((size_t)n * 4);
  size_t zero_span = off;                       // deg+cursor+zsum (+gaps)
  float*  dinv   = (float*)take((size_t)n * 4);
  int*    rp     = (int*)take((size_t)(n + 1) * 4);
  int*    bsum   = (int*)take(1024 * 4);
  float2* zd     = (float2*)take((size_t)n * 8);
  int*    col    = (int*)take((size_t)e * 4);
  float*  g      = (float*)take((size_t)n * 128 * 4);
  (void)ws_size;

  hipMemsetAsync(d_ws, 0, zero_span, stream);

  int nb = (n + 1023) / 1024;
  k_deg<<<(e + 255) / 256, 256, 0, stream>>>(dst, deg, e);
  k_scan1<<<nb, 1024, 0, stream>>>(deg, rp, bsum, n);
  k_scan2<<<1, 128, 0, stream>>>(bsum, nb);
  k_scan3<<<nb, 1024, 0, stream>>>(rp, bsum, n, e);
  k_dinv<<<(n + 255) / 256, 256, 0, stream>>>(deg, dinv, n);
  k_scatter<<<(e + 255) / 256, 256, 0, stream>>>(src, dst, x, dinv, zsum, rp, cursor, col, e);
  k_z<<<(n + 255) / 256, 256, 0, stream>>>(x, dinv, zsum, zd, n);
  k_agg<<<(n + 3) / 4, 256, 0, stream>>>(zd, rp, col, W1, b1, g, n);
  dim3 gg((n + 63) / 64, 4);
  k_gemm<<<gg, 256, 65536, stream>>>(g, W2, b2, out, n);
}

// Round 2
// 371.419 us; speedup vs baseline: 1.7178x; 1.7178x over previous
//
#include <hip/hip_runtime.h>

#define RNG 16384   // nodes per range block (64KB LDS counters)
#define EB  64      // edge chunks

// ---------------- CSR build: no global atomics ----------------

__global__ void k_hist(const int* __restrict__ dstv, unsigned* __restrict__ partial,
                       int n, int e, int ce) {
  __shared__ unsigned cnt[RNG];
  int tid = threadIdx.x;
  for (int r = tid; r < RNG; r += 512) cnt[r] = 0;
  __syncthreads();
  int lo = blockIdx.y * RNG;
  int e0 = blockIdx.x * ce;
  int e1 = min(e0 + ce, e);
  for (int i = e0 + tid; i < e1; i += 512) {
    unsigned r = (unsigned)(dstv[i] - lo);
    if (r < RNG) atomicAdd(&cnt[r], 1u);
  }
  __syncthreads();
  unsigned* prow = partial + (size_t)blockIdx.x * n;
  for (int r = tid; r < RNG; r += 512) {
    int v = lo + r;
    if (v < n) prow[v] = cnt[r];
  }
}

// partial[eb][v] -> in-place exclusive prefix over eb (base), deg, dinv, xd
__global__ void k_base(unsigned* __restrict__ partial, const float* __restrict__ x,
                       int* __restrict__ deg, float* __restrict__ dinv,
                       float* __restrict__ xd, int n) {
  int v = blockIdx.x * blockDim.x + threadIdx.x;
  if (v >= n) return;
  unsigned run = 0;
  for (int eb = 0; eb < EB; eb++) {
    size_t idx = (size_t)eb * n + v;
    unsigned c = partial[idx];
    partial[idx] = run;
    run += c;
  }
  deg[v] = (int)run;
  float di = rsqrtf((float)run + 1.0f);  // +1 self loop, always > 0
  dinv[v] = di;
  xd[v] = x[v] * di;
}

__global__ void k_scan1(const int* __restrict__ deg, int* __restrict__ rp,
                        int* __restrict__ bsum, int n) {
  __shared__ int s[1024];
  int i = blockIdx.x * 1024 + threadIdx.x;
  int v = (i < n) ? deg[i] : 0;
  s[threadIdx.x] = v;
  __syncthreads();
  for (int off = 1; off < 1024; off <<= 1) {
    int t = (threadIdx.x >= off) ? s[threadIdx.x - off] : 0;
    __syncthreads();
    s[threadIdx.x] += t;
    __syncthreads();
  }
  if (i < n) rp[i] = s[threadIdx.x] - v;  // exclusive within block
  if (threadIdx.x == 1023) bsum[blockIdx.x] = s[1023];
}

__global__ void k_scan2(int* __restrict__ bsum, int nb) {
  __shared__ int s[128];
  int v = (threadIdx.x < nb) ? bsum[threadIdx.x] : 0;
  s[threadIdx.x] = v;
  __syncthreads();
  for (int off = 1; off < 128; off <<= 1) {
    int t = (threadIdx.x >= off) ? s[threadIdx.x - off] : 0;
    __syncthreads();
    s[threadIdx.x] += t;
    __syncthreads();
  }
  if (threadIdx.x < nb) bsum[threadIdx.x] = s[threadIdx.x] - v;  // exclusive
}

__global__ void k_scan3(int* __restrict__ rp, const int* __restrict__ bsum, int n, int e) {
  int i = blockIdx.x * 1024 + threadIdx.x;
  if (i < n) rp[i] += bsum[blockIdx.x];
  if (i == 0) rp[n] = e;
}

__global__ void k_fill(const int* __restrict__ src, const int* __restrict__ dstv,
                       const int* __restrict__ rp, const unsigned* __restrict__ base,
                       int* __restrict__ col, int n, int e, int ce) {
  __shared__ unsigned cur[RNG];
  int tid = threadIdx.x;
  for (int r = tid; r < RNG; r += 512) cur[r] = 0;
  __syncthreads();
  int lo = blockIdx.y * RNG;
  int e0 = blockIdx.x * ce;
  int e1 = min(e0 + ce, e);
  const unsigned* brow = base + (size_t)blockIdx.x * n;
  for (int i = e0 + tid; i < e1; i += 512) {
    int d = dstv[i];
    unsigned r = (unsigned)(d - lo);
    if (r < RNG) {
      unsigned pos = atomicAdd(&cur[r], 1u);  // LDS atomic only
      col[rp[d] + (int)brow[d] + (int)pos] = src[i];
    }
  }
}

// ---------------- layer 1 scalar + z ----------------

__global__ void k_z(const float* __restrict__ xd, const float* __restrict__ dinv,
                    const int* __restrict__ rp, const int* __restrict__ col,
                    float2* __restrict__ zd, int n) {
  int v = blockIdx.x * blockDim.x + threadIdx.x;
  if (v >= n) return;
  int jb = rp[v], je = rp[v + 1];
  float s = 0.f;
  for (int j = jb; j < je; j++) s += xd[col[j]];
  float di = dinv[v];
  zd[v] = make_float2(di * (s + xd[v]), di);
}

// ---------------- layer 1 expand + layer 2 aggregate ----------------
// one wave per node: lanes = features (2 each), neighbors loaded lane-parallel
// then broadcast via shfl. g[v,f] = dinv[v] * ( sum_u relu(z_u*W1[f]+b1[f])*dinv_u
//                                               + relu(z_v*W1[f]+b1[f])*dinv_v )
__global__ void k_agg(const float2* __restrict__ zd, const int* __restrict__ rp,
                      const int* __restrict__ col, const float* __restrict__ W1,
                      const float* __restrict__ b1, float* __restrict__ g, int n) {
  int wid = (int)((blockIdx.x * (size_t)blockDim.x + threadIdx.x) >> 6);
  int lane = threadIdx.x & 63;
  if (wid >= n) return;
  float w0 = W1[lane], w1 = W1[lane + 64];
  float c0 = b1[lane], c1 = b1[lane + 64];
  float a0 = 0.f, a1 = 0.f;
  int jb = rp[wid], je = rp[wid + 1];
  for (int j0 = jb; j0 < je; j0 += 64) {
    int cnt = min(64, je - j0);
    float px = 0.f, py = 0.f;
    if (j0 + lane < je) {
      int u = col[j0 + lane];
      float2 p = zd[u];
      px = p.x; py = p.y;
    }
    for (int i = 0; i < cnt; ++i) {
      float zx = __shfl(px, i);
      float dy = __shfl(py, i);
      float h0 = fmaxf(zx * w0 + c0, 0.f);
      float h1 = fmaxf(zx * w1 + c1, 0.f);
      a0 += h0 * dy;
      a1 += h1 * dy;
    }
  }
  float2 pv = zd[wid];
  a0 += fmaxf(pv.x * w0 + c0, 0.f) * pv.y;
  a1 += fmaxf(pv.x * w1 + c1, 0.f) * pv.y;
  g[(size_t)wid * 128 + lane] = a0 * pv.y;
  g[(size_t)wid * 128 + lane + 64] = a1 * pv.y;
}

// ---------------- layer 2 GEMM ----------------
// out[v,o] = relu( sum_k g[v,k]*W2[k,o] + b2[o] )
// block: 64 nodes x 64 outputs, 256 threads, acc[4][4]/thread.
__global__ void k_gemm(const float* __restrict__ g, const float* __restrict__ W2,
                       const float* __restrict__ b2, float* __restrict__ out, int n) {
  extern __shared__ float smem[];
  float* gl = smem;          // 128*64
  float* wl = smem + 8192;   // 128*64
  int tid = threadIdx.x;
  int m_base = blockIdx.x * 64;
  int o_base = blockIdx.y * 64;

  {
    int k = tid >> 1;
    int half = tid & 1;
    const float* wsrc = W2 + (size_t)k * 256 + o_base + half * 32;
    float* wdst = wl + k * 64 + half * 32;
#pragma unroll
    for (int i = 0; i < 8; i++)
      *(float4*)(wdst + i * 4) = *(const float4*)(wsrc + i * 4);
  }
  {
    int row = tid >> 2;
    int cseg = (tid & 3) * 32;
    int v = m_base + row;
#pragma unroll
    for (int i = 0; i < 8; i++) {
      int c = cseg + i * 4;
      float4 val = make_float4(0.f, 0.f, 0.f, 0.f);
      if (v < n) val = *(const float4*)(g + (size_t)v * 128 + c);
      float vv[4] = {val.x, val.y, val.z, val.w};
#pragma unroll
      for (int j = 0; j < 4; j++) {
        int k = c + j;
        int sw = ((((row >> 2) ^ (k & 15)) << 2) | (row & 3));
        gl[k * 64 + sw] = vv[j];
      }
    }
  }
  __syncthreads();

  int mg = tid & 15;
  int o0 = (tid >> 4) * 4;
  float acc[4][4];
#pragma unroll
  for (int i = 0; i < 4; i++)
#pragma unroll
    for (int j = 0; j < 4; j++) acc[i][j] = 0.f;

#pragma unroll 4
  for (int k = 0; k < 128; k++) {
    float4 a = *(const float4*)(gl + k * 64 + ((mg ^ (k & 15)) << 2));
    float4 w = *(const float4*)(wl + k * 64 + o0);
    float av[4] = {a.x, a.y, a.z, a.w};
    float wv[4] = {w.x, w.y, w.z, w.w};
#pragma unroll
    for (int i = 0; i < 4; i++)
#pragma unroll
      for (int j = 0; j < 4; j++) acc[i][j] += av[i] * wv[j];
  }

  float4 bb = *(const float4*)(b2 + o_base + o0);
  float bv[4] = {bb.x, bb.y, bb.z, bb.w};
#pragma unroll
  for (int i = 0; i < 4; i++) {
    int v = m_base + mg * 4 + i;
    if (v < n) {
      float4 r;
      r.x = fmaxf(acc[i][0] + bv[0], 0.f);
      r.y = fmaxf(acc[i][1] + bv[1], 0.f);
      r.z = fmaxf(acc[i][2] + bv[2], 0.f);
      r.w = fmaxf(acc[i][3] + bv[3], 0.f);
      *(float4*)(out + (size_t)v * 256 + o_base + o0) = r;
    }
  }
}

// ---------------- launch ----------------

extern "C" void kernel_launch(void* const* d_in, const int* in_sizes, int n_in,
                              void* d_out, int out_size, void* d_ws, size_t ws_size,
                              hipStream_t stream) {
  const float* x  = (const float*)d_in[0];
  const int*   ei = (const int*)d_in[1];
  const float* W1 = (const float*)d_in[2];
  const float* b1 = (const float*)d_in[3];
  const float* W2 = (const float*)d_in[4];
  const float* b2 = (const float*)d_in[5];
  float* out = (float*)d_out;

  int n = in_sizes[0];
  int e = in_sizes[1] / 2;
  const int* src = ei;
  const int* dst = ei + e;

  char* ws = (char*)d_ws;
  size_t off = 0;
  auto take = [&](size_t bytes) -> char* {
    char* p = ws + off;
    off = (off + bytes + 255) & ~(size_t)255;
    return p;
  };
  unsigned* partial = (unsigned*)take((size_t)EB * n * 4);  // -> base (in place)
  int*    deg  = (int*)take((size_t)n * 4);
  float*  dinv = (float*)take((size_t)n * 4);
  float*  xd   = (float*)take((size_t)n * 4);
  int*    rp   = (int*)take((size_t)(n + 1) * 4);
  int*    bsum = (int*)take(1024 * 4);
  float2* zd   = (float2*)take((size_t)n * 8);
  int*    col  = (int*)take((size_t)e * 4);
  float*  g    = (float*)take((size_t)n * 128 * 4);
  (void)ws_size;

  int ce = (e + EB - 1) / EB;
  dim3 gh(EB, (n + RNG - 1) / RNG);
  int nb = (n + 1023) / 1024;

  k_hist<<<gh, 512, 0, stream>>>(dst, partial, n, e, ce);
  k_base<<<(n + 255) / 256, 256, 0, stream>>>(partial, x, deg, dinv, xd, n);
  k_scan1<<<nb, 1024, 0, stream>>>(deg, rp, bsum, n);
  k_scan2<<<1, 128, 0, stream>>>(bsum, nb);
  k_scan3<<<nb, 1024, 0, stream>>>(rp, bsum, n, e);
  k_fill<<<gh, 512, 0, stream>>>(src, dst, rp, partial, col, n, e, ce);
  k_z<<<(n + 255) / 256, 256, 0, stream>>>(xd, dinv, rp, col, zd, n);
  k_agg<<<(n + 3) / 4, 256, 0, stream>>>(zd, rp, col, W1, b1, g, n);
  dim3 gg((n + 63) / 64, 4);
  k_gemm<<<gg, 256, 65536, stream>>>(g, W2, b2, out, n);
}

// Round 3
// 303.443 us; speedup vs baseline: 2.1026x; 1.2240x over previous
//
#include <hip/hip_runtime.h>

#define RNG 16384   // nodes per range block (64KB LDS counters)
#define EB  64      // edge chunks

typedef short s16x8 __attribute__((ext_vector_type(8)));
typedef float f32x4 __attribute__((ext_vector_type(4)));

__device__ inline unsigned short bf16rne(float f) {
  union { float f; unsigned u; } cv; cv.f = f;
  unsigned r = cv.u + 0x7FFFu + ((cv.u >> 16) & 1u);
  return (unsigned short)(r >> 16);
}
__device__ inline float bf16tof(unsigned short h) {
  union { unsigned u; float f; } cv; cv.u = ((unsigned)h) << 16;
  return cv.f;
}

// ---------------- CSR build: no global atomics ----------------

__global__ void k_hist(const int* __restrict__ dstv, unsigned* __restrict__ partial,
                       int n, int e, int ce) {
  __shared__ unsigned cnt[RNG];
  int tid = threadIdx.x;
  for (int r = tid; r < RNG; r += 512) cnt[r] = 0;
  __syncthreads();
  int lo = blockIdx.y * RNG;
  int e0 = blockIdx.x * ce;
  int e1 = min(e0 + ce, e);
  for (int i = e0 + tid; i < e1; i += 512) {
    unsigned r = (unsigned)(dstv[i] - lo);
    if (r < RNG) atomicAdd(&cnt[r], 1u);
  }
  __syncthreads();
  unsigned* prow = partial + (size_t)blockIdx.x * n;
  for (int r = tid; r < RNG; r += 512) {
    int v = lo + r;
    if (v < n) prow[v] = cnt[r];
  }
}

__global__ void k_base(unsigned* __restrict__ partial, const float* __restrict__ x,
                       int* __restrict__ deg, float* __restrict__ dinv,
                       float* __restrict__ xd, int n) {
  int v = blockIdx.x * blockDim.x + threadIdx.x;
  if (v >= n) return;
  unsigned run = 0;
  for (int eb = 0; eb < EB; eb++) {
    size_t idx = (size_t)eb * n + v;
    unsigned c = partial[idx];
    partial[idx] = run;
    run += c;
  }
  deg[v] = (int)run;
  float di = rsqrtf((float)run + 1.0f);
  dinv[v] = di;
  xd[v] = x[v] * di;
}

__global__ void k_scan1(const int* __restrict__ deg, int* __restrict__ rp,
                        int* __restrict__ bsum, int n) {
  __shared__ int s[1024];
  int i = blockIdx.x * 1024 + threadIdx.x;
  int v = (i < n) ? deg[i] : 0;
  s[threadIdx.x] = v;
  __syncthreads();
  for (int off = 1; off < 1024; off <<= 1) {
    int t = (threadIdx.x >= off) ? s[threadIdx.x - off] : 0;
    __syncthreads();
    s[threadIdx.x] += t;
    __syncthreads();
  }
  if (i < n) rp[i] = s[threadIdx.x] - v;
  if (threadIdx.x == 1023) bsum[blockIdx.x] = s[1023];
}

__global__ void k_scan2(int* __restrict__ bsum, int nb) {
  __shared__ int s[128];
  int v = (threadIdx.x < nb) ? bsum[threadIdx.x] : 0;
  s[threadIdx.x] = v;
  __syncthreads();
  for (int off = 1; off < 128; off <<= 1) {
    int t = (threadIdx.x >= off) ? s[threadIdx.x - off] : 0;
    __syncthreads();
    s[threadIdx.x] += t;
    __syncthreads();
  }
  if (threadIdx.x < nb) bsum[threadIdx.x] = s[threadIdx.x] - v;
}

__global__ void k_scan3(int* __restrict__ rp, const int* __restrict__ bsum, int n, int e) {
  int i = blockIdx.x * 1024 + threadIdx.x;
  if (i < n) rp[i] += bsum[blockIdx.x];
  if (i == 0) rp[n] = e;
}

__global__ void k_fill(const int* __restrict__ src, const int* __restrict__ dstv,
                       const int* __restrict__ rp, const unsigned* __restrict__ base,
                       int* __restrict__ col, int n, int e, int ce) {
  __shared__ unsigned cur[RNG];
  int tid = threadIdx.x;
  for (int r = tid; r < RNG; r += 512) cur[r] = 0;
  __syncthreads();
  int lo = blockIdx.y * RNG;
  int e0 = blockIdx.x * ce;
  int e1 = min(e0 + ce, e);
  const unsigned* brow = base + (size_t)blockIdx.x * n;
  for (int i = e0 + tid; i < e1; i += 512) {
    int d = dstv[i];
    unsigned r = (unsigned)(d - lo);
    if (r < RNG) {
      unsigned pos = atomicAdd(&cur[r], 1u);
      col[rp[d] + (int)brow[d] + (int)pos] = src[i];
    }
  }
}

// ---------------- layer 1 scalar + z ----------------

__global__ void k_z(const float* __restrict__ xd, const float* __restrict__ dinv,
                    const int* __restrict__ rp, const int* __restrict__ col,
                    float2* __restrict__ zd, int n) {
  int v = blockIdx.x * blockDim.x + threadIdx.x;
  if (v >= n) return;
  int jb = rp[v], je = rp[v + 1];
  float s = 0.f;
  for (int j = jb; j < je; j++) s += xd[col[j]];
  float di = dinv[v];
  zd[v] = make_float2(di * (s + xd[v]), di);
}

// ---------------- layer 1 expand + layer 2 aggregate ----------------
__global__ void k_agg(const float2* __restrict__ zd, const int* __restrict__ rp,
                      const int* __restrict__ col, const float* __restrict__ W1,
                      const float* __restrict__ b1,
                      unsigned short* __restrict__ ghi, unsigned short* __restrict__ glo,
                      int n) {
  int wid = (int)((blockIdx.x * (size_t)blockDim.x + threadIdx.x) >> 6);
  int lane = threadIdx.x & 63;
  if (wid >= n) return;
  float w0 = W1[lane], w1 = W1[lane + 64];
  float c0 = b1[lane], c1 = b1[lane + 64];
  float a0 = 0.f, a1 = 0.f;
  int jb = rp[wid], je = rp[wid + 1];
  for (int j0 = jb; j0 < je; j0 += 64) {
    int cnt = min(64, je - j0);
    float px = 0.f, py = 0.f;
    if (j0 + lane < je) {
      int u = col[j0 + lane];
      float2 p = zd[u];
      px = p.x; py = p.y;
    }
    for (int i = 0; i < cnt; ++i) {
      float zx = __shfl(px, i);
      float dy = __shfl(py, i);
      float h0 = fmaxf(zx * w0 + c0, 0.f);
      float h1 = fmaxf(zx * w1 + c1, 0.f);
      a0 += h0 * dy;
      a1 += h1 * dy;
    }
  }
  float2 pv = zd[wid];
  a0 += fmaxf(pv.x * w0 + c0, 0.f) * pv.y;
  a1 += fmaxf(pv.x * w1 + c1, 0.f) * pv.y;
  float v0 = a0 * pv.y, v1 = a1 * pv.y;
  unsigned short h0 = bf16rne(v0);
  unsigned short h1 = bf16rne(v1);
  size_t b = (size_t)wid * 128 + lane;
  ghi[b] = h0;
  glo[b] = bf16rne(v0 - bf16tof(h0));
  ghi[b + 64] = h1;
  glo[b + 64] = bf16rne(v1 - bf16tof(h1));
}

// ---------------- W2 split + transpose: W2T[o][k] hi/lo bf16 ----------------
__global__ void k_wsplit(const float* __restrict__ W2,
                         unsigned short* __restrict__ w2thi,
                         unsigned short* __restrict__ w2tlo) {
  int t = blockIdx.x * 256 + threadIdx.x;   // 32768 = 128k x 256o
  int k = t >> 8, o = t & 255;
  float v = W2[t];
  unsigned short h = bf16rne(v);
  w2thi[o * 128 + k] = h;
  w2tlo[o * 128 + k] = bf16rne(v - bf16tof(h));
}

// ---------------- layer 2 GEMM via bf16x3 split MFMA ----------------
// tile M=64 x N=128, K=128 in two 64-halves. 4 waves, wave = 32 o-cols.
// LDS slot-swizzle: 16B slot s at row r stored at s^(r&7). <=2-way conflicts.
__global__ __launch_bounds__(256) void k_gemm2(
    const unsigned short* __restrict__ ghi, const unsigned short* __restrict__ glo,
    const unsigned short* __restrict__ w2thi, const unsigned short* __restrict__ w2tlo,
    const float* __restrict__ b2, float* __restrict__ out, int n) {
  __shared__ unsigned short lds[24576];  // 48KB: Ah[4096] Al[4096] Bh[8192] Bl[8192]
  unsigned short* Ah = lds;
  unsigned short* Al = lds + 4096;
  unsigned short* Bh = lds + 8192;
  unsigned short* Bl = lds + 16384;
  int tid = threadIdx.x;
  int lane = tid & 63;
  int wv = tid >> 6;
  int mbase = blockIdx.x * 64;
  int obase = blockIdx.y * 128;

  f32x4 acc[4][2];
#pragma unroll
  for (int i = 0; i < 4; i++)
#pragma unroll
    for (int j = 0; j < 2; j++) acc[i][j] = (f32x4){0.f, 0.f, 0.f, 0.f};

  for (int kh = 0; kh < 2; ++kh) {
    if (kh) __syncthreads();
    // stage A: 64 rows x 8 slots per plane; thread: row=tid>>2, slots (tid&3)*2+{0,1}
    {
      int r = tid >> 2;
      int s0 = (tid & 3) * 2;
      int rr = mbase + r; if (rr >= n) rr = n - 1;
      const unsigned short* gh = ghi + (size_t)rr * 128 + kh * 64 + s0 * 8;
      const unsigned short* gl = glo + (size_t)rr * 128 + kh * 64 + s0 * 8;
#pragma unroll
      for (int i = 0; i < 2; ++i) {
        int sw = (s0 + i) ^ (r & 7);
        *(s16x8*)(Ah + r * 64 + sw * 8) = *(const s16x8*)(gh + i * 8);
        *(s16x8*)(Al + r * 64 + sw * 8) = *(const s16x8*)(gl + i * 8);
      }
    }
    // stage B: 128 rows x 8 slots per plane; thread: row=tid>>1, slots (tid&1)*4+{0..3}
    {
      int r = tid >> 1;
      int s0 = (tid & 1) * 4;
      const unsigned short* wh = w2thi + (size_t)(obase + r) * 128 + kh * 64 + s0 * 8;
      const unsigned short* wl = w2tlo + (size_t)(obase + r) * 128 + kh * 64 + s0 * 8;
#pragma unroll
      for (int i = 0; i < 4; ++i) {
        int sw = (s0 + i) ^ (r & 7);
        *(s16x8*)(Bh + r * 64 + sw * 8) = *(const s16x8*)(wh + i * 8);
        *(s16x8*)(Bl + r * 64 + sw * 8) = *(const s16x8*)(wl + i * 8);
      }
    }
    __syncthreads();

#pragma unroll
    for (int ks = 0; ks < 2; ++ks) {
      s16x8 afh[4], afl[4], bfh[2], bfl[2];
      int kb = ks * 4 + (lane >> 4);   // slot 0..7
      int rA = lane & 15;
#pragma unroll
      for (int mt = 0; mt < 4; ++mt) {
        int row = mt * 16 + rA;
        int sw = kb ^ (row & 7);
        afh[mt] = *(const s16x8*)(Ah + row * 64 + sw * 8);
        afl[mt] = *(const s16x8*)(Al + row * 64 + sw * 8);
      }
#pragma unroll
      for (int nt = 0; nt < 2; ++nt) {
        int row = wv * 32 + nt * 16 + rA;
        int sw = kb ^ (row & 7);
        bfh[nt] = *(const s16x8*)(Bh + row * 64 + sw * 8);
        bfl[nt] = *(const s16x8*)(Bl + row * 64 + sw * 8);
      }
#pragma unroll
      for (int mt = 0; mt < 4; ++mt)
#pragma unroll
        for (int nt = 0; nt < 2; ++nt) {
          acc[mt][nt] = __builtin_amdgcn_mfma_f32_16x16x32_bf16(afh[mt], bfh[nt], acc[mt][nt], 0, 0, 0);
          acc[mt][nt] = __builtin_amdgcn_mfma_f32_16x16x32_bf16(afh[mt], bfl[nt], acc[mt][nt], 0, 0, 0);
          acc[mt][nt] = __builtin_amdgcn_mfma_f32_16x16x32_bf16(afl[mt], bfh[nt], acc[mt][nt], 0, 0, 0);
        }
    }
  }

  // epilogue: C/D layout col=lane&15, row=(lane>>4)*4+r
#pragma unroll
  for (int nt = 0; nt < 2; ++nt) {
    int o = obase + wv * 32 + nt * 16 + (lane & 15);
    float bb = b2[o];
#pragma unroll
    for (int mt = 0; mt < 4; ++mt) {
      int vr = mbase + mt * 16 + (lane >> 4) * 4;
      f32x4 a = acc[mt][nt];
#pragma unroll
      for (int r = 0; r < 4; ++r) {
        int v = vr + r;
        if (v < n) out[(size_t)v * 256 + o] = fmaxf(a[r] + bb, 0.f);
      }
    }
  }
}

// ---------------- launch ----------------

extern "C" void kernel_launch(void* const* d_in, const int* in_sizes, int n_in,
                              void* d_out, int out_size, void* d_ws, size_t ws_size,
                              hipStream_t stream) {
  const float* x  = (const float*)d_in[0];
  const int*   ei = (const int*)d_in[1];
  const float* W1 = (const float*)d_in[2];
  const float* b1 = (const float*)d_in[3];
  const float* W2 = (const float*)d_in[4];
  const float* b2 = (const float*)d_in[5];
  float* out = (float*)d_out;

  int n = in_sizes[0];
  int e = in_sizes[1] / 2;
  const int* src = ei;
  const int* dst = ei + e;

  char* ws = (char*)d_ws;
  size_t off = 0;
  auto take = [&](size_t bytes) -> char* {
    char* p = ws + off;
    off = (off + bytes + 255) & ~(size_t)255;
    return p;
  };
  unsigned* partial = (unsigned*)take((size_t)EB * n * 4);
  int*    deg   = (int*)take((size_t)n * 4);
  float*  dinv  = (float*)take((size_t)n * 4);
  float*  xd    = (float*)take((size_t)n * 4);
  int*    rp    = (int*)take((size_t)(n + 1) * 4);
  int*    bsum  = (int*)take(1024 * 4);
  float2* zd    = (float2*)take((size_t)n * 8);
  int*    col   = (int*)take((size_t)e * 4);
  unsigned short* ghi   = (unsigned short*)take((size_t)n * 128 * 2);
  unsigned short* glo   = (unsigned short*)take((size_t)n * 128 * 2);
  unsigned short* w2thi = (unsigned short*)take(256 * 128 * 2);
  unsigned short* w2tlo = (unsigned short*)take(256 * 128 * 2);
  (void)ws_size;

  int ce = (e + EB - 1) / EB;
  dim3 gh(EB, (n + RNG - 1) / RNG);
  int nb = (n + 1023) / 1024;

  k_wsplit<<<128, 256, 0, stream>>>(W2, w2thi, w2tlo);
  k_hist<<<gh, 512, 0, stream>>>(dst, partial, n, e, ce);
  k_base<<<(n + 255) / 256, 256, 0, stream>>>(partial, x, deg, dinv, xd, n);
  k_scan1<<<nb, 1024, 0, stream>>>(deg, rp, bsum, n);
  k_scan2<<<1, 128, 0, stream>>>(bsum, nb);
  k_scan3<<<nb, 1024, 0, stream>>>(rp, bsum, n, e);
  k_fill<<<gh, 512, 0, stream>>>(src, dst, rp, partial, col, n, e, ce);
  k_z<<<(n + 255) / 256, 256, 0, stream>>>(xd, dinv, rp, col, zd, n);
  k_agg<<<(n + 3) / 4, 256, 0, stream>>>(zd, rp, col, W1, b1, ghi, glo, n);
  dim3 gg((n + 63) / 64, 2);
  k_gemm2<<<gg, 256, 0, stream>>>(ghi, glo, w2thi, w2tlo, b2, out, n);
}

// Round 4
// 231.113 us; speedup vs baseline: 2.7607x; 1.3130x over previous
//
#include <hip/hip_runtime.h>

#define RNGN 128   // nodes per range (dlocal fits 7 bits)
#define RSH  7
#define PB   256   // partition blocks

typedef short s16x8 __attribute__((ext_vector_type(8)));
typedef float f32x4 __attribute__((ext_vector_type(4)));

__device__ inline unsigned short bf16rne(float f) {
  union { float f; unsigned u; } cv; cv.f = f;
  unsigned r = cv.u + 0x7FFFu + ((cv.u >> 16) & 1u);
  return (unsigned short)(r >> 16);
}
__device__ inline float bf16tof(unsigned short h) {
  union { unsigned u; float f; } cv; cv.u = ((unsigned)h) << 16;
  return cv.f;
}

// ---------------- CSR build: bucket partition, no global atomics ----------------

__global__ void k_count(const int* __restrict__ dstv, int* __restrict__ cntmat,
                        int e, int ce, int nr) {
  __shared__ int cnt[1024];
  int tid = threadIdx.x;
  for (int r = tid; r < nr; r += 512) cnt[r] = 0;
  __syncthreads();
  int e0 = blockIdx.x * ce, e1 = min(e0 + ce, e);
  for (int i = e0 + tid; i < e1; i += 512) atomicAdd(&cnt[dstv[i] >> RSH], 1);
  __syncthreads();
  for (int r = tid; r < nr; r += 512) cntmat[r * PB + blockIdx.x] = cnt[r];
}

__global__ void k_scan1(const int* __restrict__ in, int* __restrict__ outv,
                        int* __restrict__ bsum, int nt) {
  __shared__ int s[1024];
  int i = blockIdx.x * 1024 + threadIdx.x;
  int v = (i < nt) ? in[i] : 0;
  s[threadIdx.x] = v;
  __syncthreads();
  for (int off = 1; off < 1024; off <<= 1) {
    int t = (threadIdx.x >= off) ? s[threadIdx.x - off] : 0;
    __syncthreads();
    s[threadIdx.x] += t;
    __syncthreads();
  }
  if (i < nt) outv[i] = s[threadIdx.x] - v;  // exclusive within block
  if (threadIdx.x == 1023) bsum[blockIdx.x] = s[1023];
}

__global__ void k_scan2(int* __restrict__ bsum, int nb) {
  __shared__ int s[256];
  int v = (threadIdx.x < nb) ? bsum[threadIdx.x] : 0;
  s[threadIdx.x] = v;
  __syncthreads();
  for (int off = 1; off < 256; off <<= 1) {
    int t = (threadIdx.x >= off) ? s[threadIdx.x - off] : 0;
    __syncthreads();
    s[threadIdx.x] += t;
    __syncthreads();
  }
  if (threadIdx.x < nb) bsum[threadIdx.x] = s[threadIdx.x] - v;  // exclusive
}

__global__ void k_scan3(int* __restrict__ outv, const int* __restrict__ bsum, int nt) {
  int i = blockIdx.x * 1024 + threadIdx.x;
  if (i < nt) outv[i] += bsum[blockIdx.x];
}

__global__ void k_part(const int* __restrict__ src, const int* __restrict__ dstv,
                       const int* __restrict__ off, unsigned* __restrict__ bucket,
                       int e, int ce, int nr) {
  __shared__ int cur[1024];
  int tid = threadIdx.x;
  for (int r = tid; r < nr; r += 512) cur[r] = off[r * PB + blockIdx.x];
  __syncthreads();
  int e0 = blockIdx.x * ce, e1 = min(e0 + ce, e);
  for (int i = e0 + tid; i < e1; i += 512) {
    int d = dstv[i];
    int r = d >> RSH;
    int pos = atomicAdd(&cur[r], 1);  // LDS atomic only
    bucket[pos] = (unsigned)src[i] | ((unsigned)(d & (RNGN - 1)) << 17);
  }
}

// one block per range: histogram -> scan -> rp/dinv/xd -> place col
__global__ void k_fillz(const unsigned* __restrict__ bucket, const int* __restrict__ off,
                        const float* __restrict__ x, int* __restrict__ rp,
                        float* __restrict__ dinv, float* __restrict__ xd,
                        int* __restrict__ col, int n, int e, int nr) {
  __shared__ int cnt[RNGN];
  __shared__ int scn[RNGN];
  int r = blockIdx.x;
  int tid = threadIdx.x;
  int lo = r << RSH;
  int base0 = off[r * PB];
  int end0 = (r + 1 < nr) ? off[(r + 1) * PB] : e;
  if (tid < RNGN) cnt[tid] = 0;
  __syncthreads();
  for (int i = base0 + tid; i < end0; i += 256)
    atomicAdd(&cnt[bucket[i] >> 17], 1);
  __syncthreads();
  if (tid < RNGN) scn[tid] = cnt[tid];
  __syncthreads();
  for (int o = 1; o < RNGN; o <<= 1) {
    int t = (tid < RNGN && tid >= o) ? scn[tid - o] : 0;
    __syncthreads();
    if (tid < RNGN) scn[tid] += t;
    __syncthreads();
  }
  if (tid < RNGN) {
    int v = lo + tid;
    int ex = scn[tid] - cnt[tid];  // exclusive
    if (v <= n) rp[v] = base0 + ex;
    if (v < n) {
      float di = rsqrtf((float)cnt[tid] + 1.0f);
      dinv[v] = di;
      xd[v] = x[v] * di;
    }
    cnt[tid] = base0 + ex;  // becomes cursor
  }
  if (r == nr - 1 && tid == 255) rp[n] = e;
  __syncthreads();
  for (int i = base0 + tid; i < end0; i += 256) {
    unsigned p = bucket[i];
    int dl = p >> 17;
    int pos = atomicAdd(&cnt[dl], 1);
    col[pos] = (int)(p & 0x1FFFFu);
  }
}

// ---------------- layer 1 scalar + z ----------------

__global__ void k_z(const float* __restrict__ xd, const float* __restrict__ dinv,
                    const int* __restrict__ rp, const int* __restrict__ col,
                    float2* __restrict__ zd, int n) {
  int v = blockIdx.x * blockDim.x + threadIdx.x;
  if (v >= n) return;
  int jb = rp[v], je = rp[v + 1];
  float s = 0.f;
  for (int j = jb; j < je; j++) s += xd[col[j]];
  float di = dinv[v];
  zd[v] = make_float2(di * (s + xd[v]), di);
}

// ---------------- layer 1 expand + layer 2 aggregate ----------------
__global__ void k_agg(const float2* __restrict__ zd, const int* __restrict__ rp,
                      const int* __restrict__ col, const float* __restrict__ W1,
                      const float* __restrict__ b1,
                      unsigned short* __restrict__ ghi, unsigned short* __restrict__ glo,
                      int n) {
  int wid = (int)((blockIdx.x * (size_t)blockDim.x + threadIdx.x) >> 6);
  int lane = threadIdx.x & 63;
  if (wid >= n) return;
  float w0 = W1[lane], w1 = W1[lane + 64];
  float c0 = b1[lane], c1 = b1[lane + 64];
  float a0 = 0.f, a1 = 0.f;
  int jb = rp[wid], je = rp[wid + 1];
  for (int j0 = jb; j0 < je; j0 += 64) {
    int cnt = min(64, je - j0);
    float px = 0.f, py = 0.f;
    if (j0 + lane < je) {
      int u = col[j0 + lane];
      float2 p = zd[u];
      px = p.x; py = p.y;
    }
    for (int i = 0; i < cnt; ++i) {
      float zx = __shfl(px, i);
      float dy = __shfl(py, i);
      float h0 = fmaxf(zx * w0 + c0, 0.f);
      float h1 = fmaxf(zx * w1 + c1, 0.f);
      a0 += h0 * dy;
      a1 += h1 * dy;
    }
  }
  float2 pv = zd[wid];
  a0 += fmaxf(pv.x * w0 + c0, 0.f) * pv.y;
  a1 += fmaxf(pv.x * w1 + c1, 0.f) * pv.y;
  float v0 = a0 * pv.y, v1 = a1 * pv.y;
  unsigned short h0 = bf16rne(v0);
  unsigned short h1 = bf16rne(v1);
  size_t b = (size_t)wid * 128 + lane;
  ghi[b] = h0;
  glo[b] = bf16rne(v0 - bf16tof(h0));
  ghi[b + 64] = h1;
  glo[b + 64] = bf16rne(v1 - bf16tof(h1));
}

// ---------------- W2 split + transpose: W2T[o][k] hi/lo bf16 ----------------
__global__ void k_wsplit(const float* __restrict__ W2,
                         unsigned short* __restrict__ w2thi,
                         unsigned short* __restrict__ w2tlo) {
  int t = blockIdx.x * 256 + threadIdx.x;   // 32768 = 128k x 256o
  int k = t >> 8, o = t & 255;
  float v = W2[t];
  unsigned short h = bf16rne(v);
  w2thi[o * 128 + k] = h;
  w2tlo[o * 128 + k] = bf16rne(v - bf16tof(h));
}

// ---------------- layer 2 GEMM via bf16x3 split MFMA ----------------
__global__ __launch_bounds__(256) void k_gemm2(
    const unsigned short* __restrict__ ghi, const unsigned short* __restrict__ glo,
    const unsigned short* __restrict__ w2thi, const unsigned short* __restrict__ w2tlo,
    const float* __restrict__ b2, float* __restrict__ out, int n) {
  __shared__ unsigned short lds[24576];  // 48KB: Ah[4096] Al[4096] Bh[8192] Bl[8192]
  unsigned short* Ah = lds;
  unsigned short* Al = lds + 4096;
  unsigned short* Bh = lds + 8192;
  unsigned short* Bl = lds + 16384;
  int tid = threadIdx.x;
  int lane = tid & 63;
  int wv = tid >> 6;
  int mbase = blockIdx.x * 64;
  int obase = blockIdx.y * 128;

  f32x4 acc[4][2];
#pragma unroll
  for (int i = 0; i < 4; i++)
#pragma unroll
    for (int j = 0; j < 2; j++) acc[i][j] = (f32x4){0.f, 0.f, 0.f, 0.f};

  for (int kh = 0; kh < 2; ++kh) {
    if (kh) __syncthreads();
    {
      int r = tid >> 2;
      int s0 = (tid & 3) * 2;
      int rr = mbase + r; if (rr >= n) rr = n - 1;
      const unsigned short* gh = ghi + (size_t)rr * 128 + kh * 64 + s0 * 8;
      const unsigned short* gl = glo + (size_t)rr * 128 + kh * 64 + s0 * 8;
#pragma unroll
      for (int i = 0; i < 2; ++i) {
        int sw = (s0 + i) ^ (r & 7);
        *(s16x8*)(Ah + r * 64 + sw * 8) = *(const s16x8*)(gh + i * 8);
        *(s16x8*)(Al + r * 64 + sw * 8) = *(const s16x8*)(gl + i * 8);
      }
    }
    {
      int r = tid >> 1;
      int s0 = (tid & 1) * 4;
      const unsigned short* wh = w2thi + (size_t)(obase + r) * 128 + kh * 64 + s0 * 8;
      const unsigned short* wl = w2tlo + (size_t)(obase + r) * 128 + kh * 64 + s0 * 8;
#pragma unroll
      for (int i = 0; i < 4; ++i) {
        int sw = (s0 + i) ^ (r & 7);
        *(s16x8*)(Bh + r * 64 + sw * 8) = *(const s16x8*)(wh + i * 8);
        *(s16x8*)(Bl + r * 64 + sw * 8) = *(const s16x8*)(wl + i * 8);
      }
    }
    __syncthreads();

#pragma unroll
    for (int ks = 0; ks < 2; ++ks) {
      s16x8 afh[4], afl[4], bfh[2], bfl[2];
      int kb = ks * 4 + (lane >> 4);
      int rA = lane & 15;
#pragma unroll
      for (int mt = 0; mt < 4; ++mt) {
        int row = mt * 16 + rA;
        int sw = kb ^ (row & 7);
        afh[mt] = *(const s16x8*)(Ah + row * 64 + sw * 8);
        afl[mt] = *(const s16x8*)(Al + row * 64 + sw * 8);
      }
#pragma unroll
      for (int nt = 0; nt < 2; ++nt) {
        int row = wv * 32 + nt * 16 + rA;
        int sw = kb ^ (row & 7);
        bfh[nt] = *(const s16x8*)(Bh + row * 64 + sw * 8);
        bfl[nt] = *(const s16x8*)(Bl + row * 64 + sw * 8);
      }
#pragma unroll
      for (int mt = 0; mt < 4; ++mt)
#pragma unroll
        for (int nt = 0; nt < 2; ++nt) {
          acc[mt][nt] = __builtin_amdgcn_mfma_f32_16x16x32_bf16(afh[mt], bfh[nt], acc[mt][nt], 0, 0, 0);
          acc[mt][nt] = __builtin_amdgcn_mfma_f32_16x16x32_bf16(afh[mt], bfl[nt], acc[mt][nt], 0, 0, 0);
          acc[mt][nt] = __builtin_amdgcn_mfma_f32_16x16x32_bf16(afl[mt], bfh[nt], acc[mt][nt], 0, 0, 0);
        }
    }
  }

#pragma unroll
  for (int nt = 0; nt < 2; ++nt) {
    int o = obase + wv * 32 + nt * 16 + (lane & 15);
    float bb = b2[o];
#pragma unroll
    for (int mt = 0; mt < 4; ++mt) {
      int vr = mbase + mt * 16 + (lane >> 4) * 4;
      f32x4 a = acc[mt][nt];
#pragma unroll
      for (int r = 0; r < 4; ++r) {
        int v = vr + r;
        if (v < n) out[(size_t)v * 256 + o] = fmaxf(a[r] + bb, 0.f);
      }
    }
  }
}

// ---------------- launch ----------------

extern "C" void kernel_launch(void* const* d_in, const int* in_sizes, int n_in,
                              void* d_out, int out_size, void* d_ws, size_t ws_size,
                              hipStream_t stream) {
  const float* x  = (const float*)d_in[0];
  const int*   ei = (const int*)d_in[1];
  const float* W1 = (const float*)d_in[2];
  const float* b1 = (const float*)d_in[3];
  const float* W2 = (const float*)d_in[4];
  const float* b2 = (const float*)d_in[5];
  float* out = (float*)d_out;

  int n = in_sizes[0];
  int e = in_sizes[1] / 2;
  const int* src = ei;
  const int* dst = ei + e;

  char* ws = (char*)d_ws;
  size_t off_b = 0;
  auto take = [&](size_t bytes) -> char* {
    char* p = ws + off_b;
    off_b = (off_b + bytes + 255) & ~(size_t)255;
    return p;
  };
  int nr = (n + RNGN - 1) >> RSH;      // 782 ranges
  int nt = nr * PB;                    // cnt/off matrix elements
  int*      cntmat = (int*)take((size_t)nt * 4);
  int*      offmat = (int*)take((size_t)nt * 4);
  int*      bsum   = (int*)take(1024 * 4);
  unsigned* bucket = (unsigned*)take((size_t)e * 4);
  int*      rp     = (int*)take((size_t)(n + 1) * 4);
  float*    dinv   = (float*)take((size_t)n * 4);
  float*    xd     = (float*)take((size_t)n * 4);
  float2*   zd     = (float2*)take((size_t)n * 8);
  int*      col    = (int*)take((size_t)e * 4);
  unsigned short* ghi   = (unsigned short*)take((size_t)n * 128 * 2);
  unsigned short* glo   = (unsigned short*)take((size_t)n * 128 * 2);
  unsigned short* w2thi = (unsigned short*)take(256 * 128 * 2);
  unsigned short* w2tlo = (unsigned short*)take(256 * 128 * 2);
  (void)ws_size;

  int ce = (e + PB - 1) / PB;
  int nb = (nt + 1023) / 1024;

  k_wsplit<<<128, 256, 0, stream>>>(W2, w2thi, w2tlo);
  k_count<<<PB, 512, 0, stream>>>(dst, cntmat, e, ce, nr);
  k_scan1<<<nb, 1024, 0, stream>>>(cntmat, offmat, bsum, nt);
  k_scan2<<<1, 256, 0, stream>>>(bsum, nb);
  k_scan3<<<nb, 1024, 0, stream>>>(offmat, bsum, nt);
  k_part<<<PB, 512, 0, stream>>>(src, dst, offmat, bucket, e, ce, nr);
  k_fillz<<<nr, 256, 0, stream>>>(bucket, offmat, x, rp, dinv, xd, col, n, e, nr);
  k_z<<<(n + 255) / 256, 256, 0, stream>>>(xd, dinv, rp, col, zd, n);
  k_agg<<<(n + 3) / 4, 256, 0, stream>>>(zd, rp, col, W1, b1, ghi, glo, n);
  dim3 gg((n + 63) / 64, 2);
  k_gemm2<<<gg, 256, 0, stream>>>(ghi, glo, w2thi, w2tlo, b2, out, n);
}

// Round 5
// 208.901 us; speedup vs baseline: 3.0542x; 1.1063x over previous
//
#include <hip/hip_runtime.h>

#define RNGN 128   // nodes per range (dlocal fits 7 bits)
#define RSH  7
#define PB   256   // partition blocks

typedef short s16x8 __attribute__((ext_vector_type(8)));
typedef float f32x4 __attribute__((ext_vector_type(4)));

__device__ inline unsigned short bf16rne(float f) {
  union { float f; unsigned u; } cv; cv.f = f;
  unsigned r = cv.u + 0x7FFFu + ((cv.u >> 16) & 1u);
  return (unsigned short)(r >> 16);
}
__device__ inline float bf16tof(unsigned short h) {
  union { unsigned u; float f; } cv; cv.u = ((unsigned)h) << 16;
  return cv.f;
}
__device__ inline float rdlane(float v, int l) {
  return __int_as_float(__builtin_amdgcn_readlane(__float_as_int(v), l));
}

// ---------------- CSR build: bucket partition, no global atomics ----------------

__global__ void k_count(const int* __restrict__ dstv, int* __restrict__ cntmat,
                        int e, int ce, int nr) {
  __shared__ int cnt[1024];
  int tid = threadIdx.x;
  for (int r = tid; r < nr; r += 512) cnt[r] = 0;
  __syncthreads();
  int e0 = blockIdx.x * ce, e1 = min(e0 + ce, e);
  for (int i = e0 + tid; i < e1; i += 512) atomicAdd(&cnt[dstv[i] >> RSH], 1);
  __syncthreads();
  for (int r = tid; r < nr; r += 512) cntmat[r * PB + blockIdx.x] = cnt[r];
}

__global__ void k_scan1(const int* __restrict__ in, int* __restrict__ outv,
                        int* __restrict__ bsum, int nt) {
  __shared__ int s[1024];
  int i = blockIdx.x * 1024 + threadIdx.x;
  int v = (i < nt) ? in[i] : 0;
  s[threadIdx.x] = v;
  __syncthreads();
  for (int off = 1; off < 1024; off <<= 1) {
    int t = (threadIdx.x >= off) ? s[threadIdx.x - off] : 0;
    __syncthreads();
    s[threadIdx.x] += t;
    __syncthreads();
  }
  if (i < nt) outv[i] = s[threadIdx.x] - v;  // exclusive within block
  if (threadIdx.x == 1023) bsum[blockIdx.x] = s[1023];
}

__global__ void k_scan2(int* __restrict__ bsum, int nb) {
  __shared__ int s[256];
  int v = (threadIdx.x < nb) ? bsum[threadIdx.x] : 0;
  s[threadIdx.x] = v;
  __syncthreads();
  for (int off = 1; off < 256; off <<= 1) {
    int t = (threadIdx.x >= off) ? s[threadIdx.x - off] : 0;
    __syncthreads();
    s[threadIdx.x] += t;
    __syncthreads();
  }
  if (threadIdx.x < nb) bsum[threadIdx.x] = s[threadIdx.x] - v;  // exclusive
}

__global__ void k_scan3(int* __restrict__ outv, const int* __restrict__ bsum, int nt) {
  int i = blockIdx.x * 1024 + threadIdx.x;
  if (i < nt) outv[i] += bsum[blockIdx.x];
}

__global__ void k_part(const int* __restrict__ src, const int* __restrict__ dstv,
                       const int* __restrict__ off, unsigned* __restrict__ bucket,
                       int e, int ce, int nr) {
  __shared__ int cur[1024];
  int tid = threadIdx.x;
  for (int r = tid; r < nr; r += 512) cur[r] = off[r * PB + blockIdx.x];
  __syncthreads();
  int e0 = blockIdx.x * ce, e1 = min(e0 + ce, e);
  for (int i = e0 + tid; i < e1; i += 512) {
    int d = dstv[i];
    int r = d >> RSH;
    int pos = atomicAdd(&cur[r], 1);  // LDS atomic only
    bucket[pos] = (unsigned)src[i] | ((unsigned)(d & (RNGN - 1)) << 17);
  }
}

// one block per range: histogram -> scan -> rp/dinv/xd -> place col
__global__ void k_fillz(const unsigned* __restrict__ bucket, const int* __restrict__ off,
                        const float* __restrict__ x, int* __restrict__ rp,
                        float* __restrict__ dinv, float* __restrict__ xd,
                        int* __restrict__ col, int n, int e, int nr) {
  __shared__ int cnt[RNGN];
  __shared__ int scn[RNGN];
  int r = blockIdx.x;
  int tid = threadIdx.x;
  int lo = r << RSH;
  int base0 = off[r * PB];
  int end0 = (r + 1 < nr) ? off[(r + 1) * PB] : e;
  if (tid < RNGN) cnt[tid] = 0;
  __syncthreads();
  for (int i = base0 + tid; i < end0; i += 256)
    atomicAdd(&cnt[bucket[i] >> 17], 1);
  __syncthreads();
  if (tid < RNGN) scn[tid] = cnt[tid];
  __syncthreads();
  for (int o = 1; o < RNGN; o <<= 1) {
    int t = (tid < RNGN && tid >= o) ? scn[tid - o] : 0;
    __syncthreads();
    if (tid < RNGN) scn[tid] += t;
    __syncthreads();
  }
  if (tid < RNGN) {
    int v = lo + tid;
    int ex = scn[tid] - cnt[tid];  // exclusive
    if (v <= n) rp[v] = base0 + ex;
    if (v < n) {
      float di = rsqrtf((float)cnt[tid] + 1.0f);
      dinv[v] = di;
      xd[v] = x[v] * di;
    }
    cnt[tid] = base0 + ex;  // becomes cursor
  }
  if (r == nr - 1 && tid == 255) rp[n] = e;
  __syncthreads();
  for (int i = base0 + tid; i < end0; i += 256) {
    unsigned p = bucket[i];
    int dl = p >> 17;
    int pos = atomicAdd(&cnt[dl], 1);
    col[pos] = (int)(p & 0x1FFFFu);
  }
}

// ---------------- layer 1 scalar + z (16 lanes per node) ----------------

__global__ void k_z(const float* __restrict__ xd, const float* __restrict__ dinv,
                    const int* __restrict__ rp, const int* __restrict__ col,
                    float2* __restrict__ zd, int n) {
  int t = blockIdx.x * blockDim.x + threadIdx.x;
  int v = t >> 4;          // 16 lanes per node
  int l = t & 15;
  if (v >= n) return;
  int jb = rp[v], je = rp[v + 1];
  float s = 0.f;
  for (int j = jb + l; j < je; j += 16) s += xd[col[j]];
#pragma unroll
  for (int m = 1; m < 16; m <<= 1) s += __shfl_xor(s, m, 16);
  if (l == 0) {
    float di = dinv[v];
    zd[v] = make_float2(di * (s + xd[v]), di);
  }
}

// ---------------- layer 1 expand + layer 2 aggregate ----------------
// wave per node, lanes = 2 features each. Neighbor (z,dinv) loaded lane-parallel,
// broadcast via v_readlane (VALU, no LDS pipe), 8x unrolled, zero-padded tail.
__global__ void k_agg(const float2* __restrict__ zd, const int* __restrict__ rp,
                      const int* __restrict__ col, const float* __restrict__ W1,
                      const float* __restrict__ b1,
                      unsigned short* __restrict__ ghi, unsigned short* __restrict__ glo,
                      int n) {
  int wid = (int)((blockIdx.x * (size_t)blockDim.x + threadIdx.x) >> 6);
  int lane = threadIdx.x & 63;
  if (wid >= n) return;
  float w0 = W1[lane], w1 = W1[lane + 64];
  float c0 = b1[lane], c1 = b1[lane + 64];
  float a0 = 0.f, a1 = 0.f, b0 = 0.f, b3 = 0.f;
  int jb = rp[wid], je = rp[wid + 1];
  for (int j0 = jb; j0 < je; j0 += 64) {
    float px = 0.f, py = 0.f;
    if (j0 + lane < je) {
      int u = col[j0 + lane];
      float2 p = zd[u];
      px = p.x; py = p.y;
    }
    int cnt8 = min(64, ((je - j0) + 7) & ~7);
    for (int i = 0; i < cnt8; i += 8) {
#pragma unroll
      for (int k = 0; k < 8; k += 2) {
        {
          float zx = rdlane(px, i + k);
          float dy = rdlane(py, i + k);
          a0 += fmaxf(zx * w0 + c0, 0.f) * dy;
          a1 += fmaxf(zx * w1 + c1, 0.f) * dy;
        }
        {
          float zx = rdlane(px, i + k + 1);
          float dy = rdlane(py, i + k + 1);
          b0 += fmaxf(zx * w0 + c0, 0.f) * dy;
          b3 += fmaxf(zx * w1 + c1, 0.f) * dy;
        }
      }
    }
  }
  a0 += b0; a1 += b3;
  float2 pv = zd[wid];
  a0 += fmaxf(pv.x * w0 + c0, 0.f) * pv.y;
  a1 += fmaxf(pv.x * w1 + c1, 0.f) * pv.y;
  float v0 = a0 * pv.y, v1 = a1 * pv.y;
  unsigned short h0 = bf16rne(v0);
  unsigned short h1 = bf16rne(v1);
  size_t b = (size_t)wid * 128 + lane;
  ghi[b] = h0;
  glo[b] = bf16rne(v0 - bf16tof(h0));
  ghi[b + 64] = h1;
  glo[b + 64] = bf16rne(v1 - bf16tof(h1));
}

// ---------------- W2 split + transpose: W2T[o][k] hi/lo bf16 ----------------
__global__ void k_wsplit(const float* __restrict__ W2,
                         unsigned short* __restrict__ w2thi,
                         unsigned short* __restrict__ w2tlo) {
  int t = blockIdx.x * 256 + threadIdx.x;   // 32768 = 128k x 256o
  int k = t >> 8, o = t & 255;
  float v = W2[t];
  unsigned short h = bf16rne(v);
  w2thi[o * 128 + k] = h;
  w2tlo[o * 128 + k] = bf16rne(v - bf16tof(h));
}

// ---------------- layer 2 GEMM via bf16x3 split MFMA ----------------
__global__ __launch_bounds__(256) void k_gemm2(
    const unsigned short* __restrict__ ghi, const unsigned short* __restrict__ glo,
    const unsigned short* __restrict__ w2thi, const unsigned short* __restrict__ w2tlo,
    const float* __restrict__ b2, float* __restrict__ out, int n) {
  __shared__ unsigned short lds[24576];  // 48KB: Ah[4096] Al[4096] Bh[8192] Bl[8192]
  unsigned short* Ah = lds;
  unsigned short* Al = lds + 4096;
  unsigned short* Bh = lds + 8192;
  unsigned short* Bl = lds + 16384;
  int tid = threadIdx.x;
  int lane = tid & 63;
  int wv = tid >> 6;
  int mbase = blockIdx.x * 64;
  int obase = blockIdx.y * 128;

  f32x4 acc[4][2];
#pragma unroll
  for (int i = 0; i < 4; i++)
#pragma unroll
    for (int j = 0; j < 2; j++) acc[i][j] = (f32x4){0.f, 0.f, 0.f, 0.f};

  for (int kh = 0; kh < 2; ++kh) {
    if (kh) __syncthreads();
    {
      int r = tid >> 2;
      int s0 = (tid & 3) * 2;
      int rr = mbase + r; if (rr >= n) rr = n - 1;
      const unsigned short* gh = ghi + (size_t)rr * 128 + kh * 64 + s0 * 8;
      const unsigned short* gl = glo + (size_t)rr * 128 + kh * 64 + s0 * 8;
#pragma unroll
      for (int i = 0; i < 2; ++i) {
        int sw = (s0 + i) ^ (r & 7);
        *(s16x8*)(Ah + r * 64 + sw * 8) = *(const s16x8*)(gh + i * 8);
        *(s16x8*)(Al + r * 64 + sw * 8) = *(const s16x8*)(gl + i * 8);
      }
    }
    {
      int r = tid >> 1;
      int s0 = (tid & 1) * 4;
      const unsigned short* wh = w2thi + (size_t)(obase + r) * 128 + kh * 64 + s0 * 8;
      const unsigned short* wl = w2tlo + (size_t)(obase + r) * 128 + kh * 64 + s0 * 8;
#pragma unroll
      for (int i = 0; i < 4; ++i) {
        int sw = (s0 + i) ^ (r & 7);
        *(s16x8*)(Bh + r * 64 + sw * 8) = *(const s16x8*)(wh + i * 8);
        *(s16x8*)(Bl + r * 64 + sw * 8) = *(const s16x8*)(wl + i * 8);
      }
    }
    __syncthreads();

#pragma unroll
    for (int ks = 0; ks < 2; ++ks) {
      s16x8 afh[4], afl[4], bfh[2], bfl[2];
      int kb = ks * 4 + (lane >> 4);
      int rA = lane & 15;
#pragma unroll
      for (int mt = 0; mt < 4; ++mt) {
        int row = mt * 16 + rA;
        int sw = kb ^ (row & 7);
        afh[mt] = *(const s16x8*)(Ah + row * 64 + sw * 8);
        afl[mt] = *(const s16x8*)(Al + row * 64 + sw * 8);
      }
#pragma unroll
      for (int nt = 0; nt < 2; ++nt) {
        int row = wv * 32 + nt * 16 + rA;
        int sw = kb ^ (row & 7);
        bfh[nt] = *(const s16x8*)(Bh + row * 64 + sw * 8);
        bfl[nt] = *(const s16x8*)(Bl + row * 64 + sw * 8);
      }
#pragma unroll
      for (int mt = 0; mt < 4; ++mt)
#pragma unroll
        for (int nt = 0; nt < 2; ++nt) {
          acc[mt][nt] = __builtin_amdgcn_mfma_f32_16x16x32_bf16(afh[mt], bfh[nt], acc[mt][nt], 0, 0, 0);
          acc[mt][nt] = __builtin_amdgcn_mfma_f32_16x16x32_bf16(afh[mt], bfl[nt], acc[mt][nt], 0, 0, 0);
          acc[mt][nt] = __builtin_amdgcn_mfma_f32_16x16x32_bf16(afl[mt], bfh[nt], acc[mt][nt], 0, 0, 0);
        }
    }
  }

#pragma unroll
  for (int nt = 0; nt < 2; ++nt) {
    int o = obase + wv * 32 + nt * 16 + (lane & 15);
    float bb = b2[o];
#pragma unroll
    for (int mt = 0; mt < 4; ++mt) {
      int vr = mbase + mt * 16 + (lane >> 4) * 4;
      f32x4 a = acc[mt][nt];
#pragma unroll
      for (int r = 0; r < 4; ++r) {
        int v = vr + r;
        if (v < n) out[(size_t)v * 256 + o] = fmaxf(a[r] + bb, 0.f);
      }
    }
  }
}

// ---------------- launch ----------------

extern "C" void kernel_launch(void* const* d_in, const int* in_sizes, int n_in,
                              void* d_out, int out_size, void* d_ws, size_t ws_size,
                              hipStream_t stream) {
  const float* x  = (const float*)d_in[0];
  const int*   ei = (const int*)d_in[1];
  const float* W1 = (const float*)d_in[2];
  const float* b1 = (const float*)d_in[3];
  const float* W2 = (const float*)d_in[4];
  const float* b2 = (const float*)d_in[5];
  float* out = (float*)d_out;

  int n = in_sizes[0];
  int e = in_sizes[1] / 2;
  const int* src = ei;
  const int* dst = ei + e;

  char* ws = (char*)d_ws;
  size_t off_b = 0;
  auto take = [&](size_t bytes) -> char* {
    char* p = ws + off_b;
    off_b = (off_b + bytes + 255) & ~(size_t)255;
    return p;
  };
  int nr = (n + RNGN - 1) >> RSH;      // 782 ranges
  int nt = nr * PB;                    // cnt/off matrix elements
  int*      cntmat = (int*)take((size_t)nt * 4);
  int*      offmat = (int*)take((size_t)nt * 4);
  int*      bsum   = (int*)take(1024 * 4);
  unsigned* bucket = (unsigned*)take((size_t)e * 4);
  int*      rp     = (int*)take((size_t)(n + 1) * 4);
  float*    dinv   = (float*)take((size_t)n * 4);
  float*    xd     = (float*)take((size_t)n * 4);
  float2*   zd     = (float2*)take((size_t)n * 8);
  int*      col    = (int*)take((size_t)e * 4);
  unsigned short* ghi   = (unsigned short*)take((size_t)n * 128 * 2);
  unsigned short* glo   = (unsigned short*)take((size_t)n * 128 * 2);
  unsigned short* w2thi = (unsigned short*)take(256 * 128 * 2);
  unsigned short* w2tlo = (unsigned short*)take(256 * 128 * 2);
  (void)ws_size;

  int ce = (e + PB - 1) / PB;
  int nb = (nt + 1023) / 1024;

  k_wsplit<<<128, 256, 0, stream>>>(W2, w2thi, w2tlo);
  k_count<<<PB, 512, 0, stream>>>(dst, cntmat, e, ce, nr);
  k_scan1<<<nb, 1024, 0, stream>>>(cntmat, offmat, bsum, nt);
  k_scan2<<<1, 256, 0, stream>>>(bsum, nb);
  k_scan3<<<nb, 1024, 0, stream>>>(offmat, bsum, nt);
  k_part<<<PB, 512, 0, stream>>>(src, dst, offmat, bucket, e, ce, nr);
  k_fillz<<<nr, 256, 0, stream>>>(bucket, offmat, x, rp, dinv, xd, col, n, e, nr);
  k_z<<<(n * 16 + 255) / 256, 256, 0, stream>>>(xd, dinv, rp, col, zd, n);
  k_agg<<<(n + 3) / 4, 256, 0, stream>>>(zd, rp, col, W1, b1, ghi, glo, n);
  dim3 gg((n + 63) / 64, 2);
  k_gemm2<<<gg, 256, 0, stream>>>(ghi, glo, w2thi, w2tlo, b2, out, n);
}